// Round 9
// baseline (141.640 us; speedup 1.0000x reference)
//
#include <hip/hip_runtime.h>
#include <hip/hip_bf16.h>

#define NB 32
#define DIN 512
#define TT 4096
#define DH 500
#define DHP 512
#define EPSV 1e-12f
#define BM 64
#define LDA 520            // bf16 elems; 1040B row stride, 16B-aligned rows
#define NTILES (TT / BM)   // 64 t-tiles per batch
#define CH 8               // k-steps per prefetch chunk
#define NCH 4              // 32 k-steps / CH

typedef short short8 __attribute__((ext_vector_type(8)));
typedef float f32x16 __attribute__((ext_vector_type(16)));

__device__ inline unsigned short f2bf(float f) {
    unsigned int u = __builtin_bit_cast(unsigned int, f);
    unsigned int r = (u + 0x7fffu + ((u >> 16) & 1u)) >> 16;
    return (unsigned short)r;
}
__device__ inline float bf2f(unsigned short h) {
    unsigned int u = ((unsigned int)h) << 16;
    return __builtin_bit_cast(float, u);
}

// Kernel 0: pack w1 -> bf16 MFMA-fragment order [hb=16][ks=32][lane=64][8]
//   h = hb*32 + (lane&31),  d = ks*16 + (lane>>5)*8 + j
__global__ void prep_kernel(const float* __restrict__ w1, const float* __restrict__ w2,
                            unsigned short* __restrict__ w1b, float* __restrict__ w2f) {
    int idx = blockIdx.x * blockDim.x + threadIdx.x;
    if (idx < DHP * DIN) {
        const int j    = idx & 7;
        const int lane = (idx >> 3) & 63;
        const int ks   = (idx >> 9) & 31;
        const int hb   = idx >> 14;
        const int h = hb * 32 + (lane & 31);
        const int d = ks * 16 + (lane >> 5) * 8 + j;
        float v = (h < DH) ? w1[h * DIN + d] : 0.f;
        w1b[idx] = f2bf(v);
        if (idx < DHP) w2f[idx] = (idx < DH) ? w2[idx] : 0.f;
    }
}

// Kernel 1 (fused): per (b, 64-t tile). w1b k-loop loads are explicitly
// software-pipelined: double-buffered register chunks of CH k-steps, fully
// statically unrolled, sched_barrier(0) fences so hipcc can't sink them.
__launch_bounds__(512, 2)
__global__ void scores_fused(const float* __restrict__ x,
                             const unsigned short* __restrict__ w1b,
                             const float* __restrict__ w2f,
                             float* __restrict__ pm, float* __restrict__ pz,
                             float* __restrict__ pswx, float* __restrict__ psx,
                             float* __restrict__ psx2) {
    __shared__ unsigned short A_lds[BM][LDA];
    __shared__ float score_p[8][BM];
    __shared__ float w_lds[BM];

    const int tid = threadIdx.x;
    const int b = blockIdx.x >> 6;             // NTILES = 64 tiles per batch
    const int t0 = (blockIdx.x & 63) * BM;

    // ---- Phase 1: stage x[b, :, t0..t0+63] -> A_lds[t][d] (bf16) ----
    // R5 form: 64 lanes cover 64 consecutive t (coalesced); 0 bank conflicts.
    {
        const int ts = tid & 63;
        const int dg = tid >> 6;               // 0..7
        const float* xb = x + (size_t)b * DIN * TT + t0 + ts;
        #pragma unroll
        for (int oct = 0; oct < 8; ++oct) {
            const int d0 = dg * 64 + oct * 8;
            short8 pk;
            #pragma unroll
            for (int j = 0; j < 8; ++j)
                pk[j] = (short)f2bf(xb[(size_t)(d0 + j) * TT]);
            *reinterpret_cast<short8*>(&A_lds[ts][d0]) = pk;
        }
    }
    __syncthreads();

    // ---- Phase 2: MFMA. Wave w owns h-panels {2w,2w+1}; A=w1 (m=h),
    // B=x^T (n=t): D cols (lane&31)=t, rows=h -> relu*w2 reduce in-lane.
    const int w = tid >> 6;
    const int lane = tid & 63;
    const int lane31 = lane & 31;
    const int khalf = lane >> 5;
    const int hrow0 = w * 64;

    float w20v[16], w21v[16];
    #pragma unroll
    for (int g = 0; g < 16; ++g) {
        const int rp = (g & 3) + 8 * (g >> 2) + 4 * khalf;
        w20v[g] = w2f[hrow0 + rp];
        w21v[g] = w2f[hrow0 + 32 + rp];
    }

    f32x16 acc00, acc01, acc10, acc11;
    #pragma unroll
    for (int g = 0; g < 16; ++g) { acc00[g] = 0.f; acc01[g] = 0.f; acc10[g] = 0.f; acc11[g] = 0.f; }

    const unsigned short* base0 = w1b + (size_t)w * 32768 + (size_t)lane * 8;
    const unsigned short* base1 = base0 + 16384;
    const unsigned short* Bp0 = &A_lds[lane31][khalf * 8];
    const unsigned short* Bp1 = &A_lds[32 + lane31][khalf * 8];

    short8 a0buf[2][CH], a1buf[2][CH];         // 128 VGPR: the pipeline depth
    #pragma unroll
    for (int j = 0; j < CH; ++j) {
        a0buf[0][j] = *reinterpret_cast<const short8*>(base0 + j * 512);
        a1buf[0][j] = *reinterpret_cast<const short8*>(base1 + j * 512);
    }
    #pragma unroll
    for (int c = 0; c < NCH; ++c) {            // c compile-time: static indices
        if (c + 1 < NCH) {
            #pragma unroll
            for (int j = 0; j < CH; ++j) {
                a0buf[(c + 1) & 1][j] = *reinterpret_cast<const short8*>(base0 + ((c + 1) * CH + j) * 512);
                a1buf[(c + 1) & 1][j] = *reinterpret_cast<const short8*>(base1 + ((c + 1) * CH + j) * 512);
            }
        }
        __builtin_amdgcn_sched_barrier(0);     // pin: loads c+1 issued before MFMA c
        #pragma unroll
        for (int j = 0; j < CH; ++j) {
            const int ks = c * CH + j;
            short8 b0 = *reinterpret_cast<const short8*>(Bp0 + ks * 16);
            short8 b1 = *reinterpret_cast<const short8*>(Bp1 + ks * 16);
            acc00 = __builtin_amdgcn_mfma_f32_32x32x16_bf16(a0buf[c & 1][j], b0, acc00, 0, 0, 0);
            acc01 = __builtin_amdgcn_mfma_f32_32x32x16_bf16(a0buf[c & 1][j], b1, acc01, 0, 0, 0);
            acc10 = __builtin_amdgcn_mfma_f32_32x32x16_bf16(a1buf[c & 1][j], b0, acc10, 0, 0, 0);
            acc11 = __builtin_amdgcn_mfma_f32_32x32x16_bf16(a1buf[c & 1][j], b1, acc11, 0, 0, 0);
        }
        __builtin_amdgcn_sched_barrier(0);
    }

    float s0 = 0.f, s1 = 0.f;
    #pragma unroll
    for (int g = 0; g < 16; ++g) {
        s0 += fmaxf(acc00[g], 0.f) * w20v[g] + fmaxf(acc10[g], 0.f) * w21v[g];
        s1 += fmaxf(acc01[g], 0.f) * w20v[g] + fmaxf(acc11[g], 0.f) * w21v[g];
    }
    s0 += __shfl_xor(s0, 32, 64);
    s1 += __shfl_xor(s1, 32, 64);
    if (khalf == 0) {                          // deterministic per-wave partials
        score_p[w][lane31] = s0;
        score_p[w][32 + lane31] = s1;
    }
    __syncthreads();

    // ---- Phase 3: wave 0 finalizes scores -> e_t, m_blk, Z_blk ----
    if (tid < BM) {
        float s = 0.f;
        #pragma unroll
        for (int ww = 0; ww < 8; ++ww) s += score_p[ww][tid];
        float m = s;
        #pragma unroll
        for (int k = 1; k <= 32; k <<= 1) m = fmaxf(m, __shfl_xor(m, k, 64));
        float e = __expf(s - m);
        float Z = e;
        #pragma unroll
        for (int k = 1; k <= 32; k <<= 1) Z += __shfl_xor(Z, k, 64);
        w_lds[tid] = e;
        if (tid == 0) { pm[blockIdx.x] = m; pz[blockIdx.x] = Z; }
    }
    __syncthreads();

    // ---- Phase 4: per-d partials over the tile's 64 t ----
    {
        const int d = tid;                     // 0..511
        float sx = 0.f, sx2 = 0.f, swx = 0.f;
        #pragma unroll 8
        for (int t = 0; t < BM; ++t) {
            const float xv = bf2f(A_lds[t][d]);
            const float wv = w_lds[t];
            sx += xv; sx2 += xv * xv; swx += wv * xv;
        }
        const size_t o = (size_t)blockIdx.x * DHP + d;
        psx[o] = sx; psx2[o] = sx2; pswx[o] = swx;
    }
}

// Kernel 2: combine 64 tiles per batch -> mean, stddev
__global__ void combine_kernel(const float* __restrict__ pm, const float* __restrict__ pz,
                               const float* __restrict__ pswx, const float* __restrict__ psx,
                               const float* __restrict__ psx2, float* __restrict__ out) {
    __shared__ float sm[NTILES], sz[NTILES];
    const int b = blockIdx.x;
    const int tid = threadIdx.x;               // d = tid, 0..511
    if (tid < NTILES) { sm[tid] = pm[b * NTILES + tid]; sz[tid] = pz[b * NTILES + tid]; }
    __syncthreads();

    float mg = -1e30f;
    #pragma unroll 8
    for (int i = 0; i < NTILES; ++i) mg = fmaxf(mg, sm[i]);
    float denom = 0.f;
    #pragma unroll 8
    for (int i = 0; i < NTILES; ++i) denom += sz[i] * __expf(sm[i] - mg);

    float num = 0.f, sx = 0.f, sx2 = 0.f;
    #pragma unroll 4
    for (int i = 0; i < NTILES; ++i) {
        const size_t o = ((size_t)(b * NTILES + i)) * DHP + tid;
        const float f = __expf(sm[i] - mg);
        num += f * pswx[o];
        sx  += psx[o];
        sx2 += psx2[o];
    }
    const float mean = num / denom;
    const float ex  = sx  * (1.f / TT);
    const float ex2 = sx2 * (1.f / TT);
    float var = ex2 - 2.f * mean * ex + mean * mean;
    if (var <= EPSV) var = EPSV;
    out[(size_t)b * 1024 + tid] = mean;
    out[(size_t)b * 1024 + 512 + tid] = sqrtf(var);
}

extern "C" void kernel_launch(void* const* d_in, const int* in_sizes, int n_in,
                              void* d_out, int out_size, void* d_ws, size_t ws_size,
                              hipStream_t stream) {
    const float* x  = (const float*)d_in[0];
    const float* w1 = (const float*)d_in[1];
    const float* w2 = (const float*)d_in[2];
    float* out = (float*)d_out;

    char* ws = (char*)d_ws;
    unsigned short* w1b = (unsigned short*)ws;                    // 512 KB
    float* w2f  = (float*)(ws + 524288);                          // 2 KB
    float* pm   = (float*)(ws + 526336);                          // 8 KB
    float* pz   = (float*)(ws + 534528);                          // 8 KB
    float* pswx = (float*)(ws + 542720);                          // 4 MB
    float* psx  = pswx + (size_t)NB * NTILES * DHP;               // 4 MB
    float* psx2 = psx  + (size_t)NB * NTILES * DHP;               // 4 MB

    prep_kernel<<<(DHP * DIN + 255) / 256, 256, 0, stream>>>(w1, w2, w1b, w2f);
    scores_fused<<<NB * NTILES, 512, 0, stream>>>(x, w1b, w2f, pm, pz, pswx, psx, psx2);
    combine_kernel<<<NB, 512, 0, stream>>>(pm, pz, pswx, psx, psx2, out);
}

// Round 10
// 129.198 us; speedup vs baseline: 1.0963x; 1.0963x over previous
//
#include <hip/hip_runtime.h>
#include <hip/hip_bf16.h>

#define NB 32
#define DIN 512
#define TT 4096
#define DH 500
#define DHP 512
#define EPSV 1e-12f
#define BM 128             // t per block
#define LDA 520            // bf16 elems; 1040B row stride, 16B-aligned rows
#define NTILES (TT / BM)   // 32 t-tiles per batch
#define CHD 128            // d per chunk
#define NCHK 4             // 512 / CHD

typedef short short8 __attribute__((ext_vector_type(8)));
typedef float f32x16 __attribute__((ext_vector_type(16)));

__device__ inline unsigned short f2bf(float f) {
    unsigned int u = __builtin_bit_cast(unsigned int, f);
    unsigned int r = (u + 0x7fffu + ((u >> 16) & 1u)) >> 16;
    return (unsigned short)r;
}
__device__ inline float bf2f(unsigned short h) {
    unsigned int u = ((unsigned int)h) << 16;
    return __builtin_bit_cast(float, u);
}

// Kernel 0: pack w1 -> bf16 MFMA-fragment order [hb=16][ks=32][lane=64][8]
//   h = hb*32 + (lane&31),  d = ks*16 + (lane>>5)*8 + j
__global__ void prep_kernel(const float* __restrict__ w1, const float* __restrict__ w2,
                            unsigned short* __restrict__ w1b, float* __restrict__ w2f) {
    int idx = blockIdx.x * blockDim.x + threadIdx.x;
    if (idx < DHP * DIN) {
        const int j    = idx & 7;
        const int lane = (idx >> 3) & 63;
        const int ks   = (idx >> 9) & 31;
        const int hb   = idx >> 14;
        const int h = hb * 32 + (lane & 31);
        const int d = ks * 16 + (lane >> 5) * 8 + j;
        float v = (h < DH) ? w1[h * DIN + d] : 0.f;
        w1b[idx] = f2bf(v);
        if (idx < DHP) w2f[idx] = (idx < DH) ? w2[idx] : 0.f;
    }
}

// Kernel 1 (fused): one block per 128-t tile. x-tile staged into LDS in 4
// d-chunks; chunk c+1's global loads issue BEFORE MFMA of chunk c (T14:
// HBM latency hides under 64 MFMAs), convert+ds_write after, 1 barrier/chunk.
__launch_bounds__(512, 2)
__global__ void scores_fused(const float* __restrict__ x,
                             const unsigned short* __restrict__ w1b,
                             const float* __restrict__ w2f,
                             float* __restrict__ pm, float* __restrict__ pz,
                             float* __restrict__ pswx, float* __restrict__ psx,
                             float* __restrict__ psx2) {
    __shared__ unsigned short A_lds[BM][LDA];
    __shared__ float score_p[8][BM];
    __shared__ float w_lds[BM];
    __shared__ float red[4];

    const int tid = threadIdx.x;
    const int b  = blockIdx.x >> 5;            // NTILES = 32 tiles per batch
    const int t0 = (blockIdx.x & 31) * BM;

    // staging coords: lane-consecutive t (coalesced 256B), dg = 32-d group
    const int tsub  = tid & 63;
    const int thalf = (tid >> 6) & 1;
    const int ts    = thalf * 64 + tsub;       // t within tile, 0..127
    const int dg    = tid >> 7;                // 0..3
    const float* xb = x + (size_t)b * DIN * TT + t0 + ts;

    // MFMA coords
    const int w = tid >> 6;                    // wave: h-panels {2w,2w+1}
    const int lane = tid & 63;
    const int lane31 = lane & 31;
    const int khalf = lane >> 5;
    const int hrow0 = w * 64;
    const unsigned short* base0 = w1b + (size_t)w * 32768 + (size_t)lane * 8;
    const unsigned short* base1 = base0 + 16384;

    // ---- Prologue: stage chunk 0 ----
    {
        float xr[32];
        #pragma unroll
        for (int j = 0; j < 32; ++j)
            xr[j] = xb[(size_t)(dg * 32 + j) * TT];
        #pragma unroll
        for (int oct = 0; oct < 4; ++oct) {
            short8 pk;
            #pragma unroll
            for (int j = 0; j < 8; ++j) pk[j] = (short)f2bf(xr[oct * 8 + j]);
            *reinterpret_cast<short8*>(&A_lds[ts][dg * 32 + oct * 8]) = pk;
        }
    }
    __syncthreads();

    f32x16 acc[2][4];
    #pragma unroll
    for (int p = 0; p < 2; ++p)
        #pragma unroll
        for (int tt = 0; tt < 4; ++tt)
            #pragma unroll
            for (int g = 0; g < 16; ++g) acc[p][tt][g] = 0.f;

    // ---- Main loop: stage(c+1) loads || MFMA(c) || write(c+1) ----
    #pragma unroll
    for (int c = 0; c < NCHK; ++c) {
        float xr[32];
        if (c < NCHK - 1) {
            const int db = (c + 1) * CHD + dg * 32;
            #pragma unroll
            for (int j = 0; j < 32; ++j)
                xr[j] = xb[(size_t)(db + j) * TT];
        }
        __builtin_amdgcn_sched_barrier(0);     // pin: loads issued before MFMA

        #pragma unroll
        for (int ks = 0; ks < 8; ++ks) {
            const int k = c * 8 + ks;
            short8 a0 = *reinterpret_cast<const short8*>(base0 + k * 512);
            short8 a1 = *reinterpret_cast<const short8*>(base1 + k * 512);
            #pragma unroll
            for (int tt = 0; tt < 4; ++tt) {
                short8 bb = *reinterpret_cast<const short8*>(
                    &A_lds[tt * 32 + lane31][k * 16 + khalf * 8]);
                acc[0][tt] = __builtin_amdgcn_mfma_f32_32x32x16_bf16(a0, bb, acc[0][tt], 0, 0, 0);
                acc[1][tt] = __builtin_amdgcn_mfma_f32_32x32x16_bf16(a1, bb, acc[1][tt], 0, 0, 0);
            }
        }

        if (c < NCHK - 1) {
            const int db = (c + 1) * CHD + dg * 32;
            #pragma unroll
            for (int oct = 0; oct < 4; ++oct) {
                short8 pk;
                #pragma unroll
                for (int j = 0; j < 8; ++j) pk[j] = (short)f2bf(xr[oct * 8 + j]);
                *reinterpret_cast<short8*>(&A_lds[ts][db + oct * 8]) = pk;
            }
        }
        __syncthreads();
    }

    // ---- epilogue reduce: relu*w2 over h (in-lane rows), per t-tile ----
    #pragma unroll
    for (int tt = 0; tt < 4; ++tt) {
        float s = 0.f;
        #pragma unroll
        for (int g = 0; g < 16; ++g) {
            const int rp = (g & 3) + 8 * (g >> 2) + 4 * khalf;
            s += fmaxf(acc[0][tt][g], 0.f) * w2f[hrow0 + rp]
               + fmaxf(acc[1][tt][g], 0.f) * w2f[hrow0 + 32 + rp];
        }
        s += __shfl_xor(s, 32, 64);
        if (khalf == 0) score_p[w][tt * 32 + lane31] = s;
    }
    __syncthreads();

    // ---- softmax partial over the tile's 128 t (waves 0-1) ----
    const int tl = tid & 127;
    float sv = 0.f;
    if (tid < BM) {
        #pragma unroll
        for (int ww = 0; ww < 8; ++ww) sv += score_p[ww][tl];
    }
    float m = (tid < BM) ? sv : -1e30f;
    #pragma unroll
    for (int k = 1; k <= 32; k <<= 1) m = fmaxf(m, __shfl_xor(m, k, 64));
    if (tid == 0) red[0] = m;
    if (tid == 64) red[1] = m;
    __syncthreads();
    const float mb = fmaxf(red[0], red[1]);
    float e = 0.f, Zp = 0.f;
    if (tid < BM) { e = __expf(sv - mb); Zp = e; }
    #pragma unroll
    for (int k = 1; k <= 32; k <<= 1) Zp += __shfl_xor(Zp, k, 64);
    if (tid == 0) red[2] = Zp;
    if (tid == 64) red[3] = Zp;
    if (tid < BM) w_lds[tl] = e;
    __syncthreads();
    if (tid == 0) { pm[blockIdx.x] = mb; pz[blockIdx.x] = red[2] + red[3]; }

    // ---- phase 4: per-d partials over the tile's 128 t ----
    {
        const int d = tid;                     // 0..511
        float sx = 0.f, sx2 = 0.f, swx = 0.f;
        #pragma unroll 8
        for (int t = 0; t < BM; ++t) {
            const float xv = bf2f(A_lds[t][d]);
            const float wv = w_lds[t];
            sx += xv; sx2 += xv * xv; swx += wv * xv;
        }
        const size_t o = (size_t)blockIdx.x * DHP + d;
        psx[o] = sx; psx2[o] = sx2; pswx[o] = swx;
    }
}

// Kernel 2: combine 32 tiles per batch -> mean, stddev
__global__ void combine_kernel(const float* __restrict__ pm, const float* __restrict__ pz,
                               const float* __restrict__ pswx, const float* __restrict__ psx,
                               const float* __restrict__ psx2, float* __restrict__ out) {
    __shared__ float sm[NTILES], sz[NTILES];
    const int b = blockIdx.x;
    const int tid = threadIdx.x;               // d = tid, 0..511
    if (tid < NTILES) { sm[tid] = pm[b * NTILES + tid]; sz[tid] = pz[b * NTILES + tid]; }
    __syncthreads();

    float mg = -1e30f;
    #pragma unroll 8
    for (int i = 0; i < NTILES; ++i) mg = fmaxf(mg, sm[i]);
    float denom = 0.f;
    #pragma unroll 8
    for (int i = 0; i < NTILES; ++i) denom += sz[i] * __expf(sm[i] - mg);

    float num = 0.f, sx = 0.f, sx2 = 0.f;
    #pragma unroll 4
    for (int i = 0; i < NTILES; ++i) {
        const size_t o = ((size_t)(b * NTILES + i)) * DHP + tid;
        const float f = __expf(sm[i] - mg);
        num += f * pswx[o];
        sx  += psx[o];
        sx2 += psx2[o];
    }
    const float mean = num / denom;
    const float ex  = sx  * (1.f / TT);
    const float ex2 = sx2 * (1.f / TT);
    float var = ex2 - 2.f * mean * ex + mean * mean;
    if (var <= EPSV) var = EPSV;
    out[(size_t)b * 1024 + tid] = mean;
    out[(size_t)b * 1024 + 512 + tid] = sqrtf(var);
}

extern "C" void kernel_launch(void* const* d_in, const int* in_sizes, int n_in,
                              void* d_out, int out_size, void* d_ws, size_t ws_size,
                              hipStream_t stream) {
    const float* x  = (const float*)d_in[0];
    const float* w1 = (const float*)d_in[1];
    const float* w2 = (const float*)d_in[2];
    float* out = (float*)d_out;

    char* ws = (char*)d_ws;
    unsigned short* w1b = (unsigned short*)ws;                    // 512 KB
    float* w2f  = (float*)(ws + 524288);                          // 2 KB
    float* pm   = (float*)(ws + 526336);                          // 4 KB
    float* pz   = (float*)(ws + 530432);                          // 4 KB
    float* pswx = (float*)(ws + 534528);                          // 2 MB
    float* psx  = pswx + (size_t)NB * NTILES * DHP;               // 2 MB
    float* psx2 = psx  + (size_t)NB * NTILES * DHP;               // 2 MB

    prep_kernel<<<(DHP * DIN + 255) / 256, 256, 0, stream>>>(w1, w2, w1b, w2f);
    scores_fused<<<NB * NTILES, 512, 0, stream>>>(x, w1b, w2f, pm, pz, pswx, psx, psx2);
    combine_kernel<<<NB, 512, 0, stream>>>(pm, pz, pswx, psx, psx2, out);
}